// Round 2
// baseline (457.454 us; speedup 1.0000x reference)
//
#include <hip/hip_runtime.h>

// ForwardBackwardImputer: reference collapses to pure forward-fill:
//   out[b,l,:] = x[b, F(b,l), :],  F(b,l) = cummax_{l'<=l}( valid(l') ? l' : 0 )
//   valid(l) <=> NOT all |x[b,l,d]| <= 1e-6
// (Reference's backward-fill branch is provably x[b,0,:] on exactly the rows
//  where forward-fill also yields x[b,0,:] — a no-op. Verified absmax=0 in R0.)
//
// R1 structure: 2 kernels.
//  A: grid-stride, 4 rows in flight per thread: validity + copy-through + idx.
//  BC: 1 block/batch: LDS max-scan of idx, compact missing list, gather-fill.

constexpr int Bn = 256;
constexpr int Ln = 2048;
constexpr int Dn = 128;          // 128 f32 = 512 B per row; 32 float4 lanes
constexpr int ROWS = Bn * Ln;    // 524288
constexpr float A_TOL = 1e-6f;

constexpr int A_BLOCKS = 8192;   // G = 65536 groups; ROWS/(4G) = 2 iterations

// ---------------------------------------------------------------------------
// Kernel A
// ---------------------------------------------------------------------------
__global__ __launch_bounds__(256) void
kernelA(const float* __restrict__ x, float* __restrict__ out,
        int* __restrict__ idx) {
    const int tid  = blockIdx.x * 256 + threadIdx.x;
    const int g    = tid >> 5;                 // 32-lane group id
    const int lane = tid & 31;
    const int G    = (gridDim.x * 256) >> 5;   // total groups
    const int shift = threadIdx.x & 32;        // 0 or 32: which wave half

    // ROWS divisible by 4*G (524288 = 2 * 262144) -> no tail handling needed.
    for (int r0 = g; r0 < ROWS; r0 += 4 * G) {
        int r[4] = {r0, r0 + G, r0 + 2 * G, r0 + 3 * G};
        float4 v[4];
        #pragma unroll
        for (int k = 0; k < 4; ++k)
            v[k] = ((const float4*)x)[(size_t)r[k] * 32 + lane];

        #pragma unroll
        for (int k = 0; k < 4; ++k) {
            const bool near0 = (__builtin_fabsf(v[k].x) <= A_TOL) &
                               (__builtin_fabsf(v[k].y) <= A_TOL) &
                               (__builtin_fabsf(v[k].z) <= A_TOL) &
                               (__builtin_fabsf(v[k].w) <= A_TOL);
            const unsigned long long bal = __ballot(near0);
            const unsigned int mine = (unsigned int)(bal >> shift);
            const bool missing = (mine == 0xffffffffu);
            const int l = r[k] & (Ln - 1);
            if (!missing || l == 0)
                ((float4*)out)[(size_t)r[k] * 32 + lane] = v[k];
            if (lane == 0)
                idx[r[k]] = missing ? 0 : l;
        }
    }
}

// ---------------------------------------------------------------------------
// Kernel BC: one block per batch b.
//  Phase 1: inclusive max-scan of idx[b,*] -> F[] in LDS.
//  Phase 2: compact {l : F[l] != l} into list[] (atomicAdd on LDS counter).
//  Phase 3: 8 groups x 32 lanes gather-copy missing rows.
// ---------------------------------------------------------------------------
__global__ __launch_bounds__(256) void
kernelBC(const float* __restrict__ x, float* __restrict__ out,
         const int* __restrict__ idx) {
    __shared__ int F[Ln];
    __shared__ int s[256];
    __shared__ int list[Ln];
    __shared__ int cnt;

    const int b = blockIdx.x;
    const int t = threadIdx.x;

    // Phase 1: load 8 ints/thread, thread-local scan + Hillis-Steele partials.
    const int* base = idx + (size_t)b * Ln + t * 8;
    int4 a0 = ((const int4*)base)[0];
    int4 a1 = ((const int4*)base)[1];
    int v[8] = {a0.x, a0.y, a0.z, a0.w, a1.x, a1.y, a1.z, a1.w};

    int m = 0;
    #pragma unroll
    for (int i = 0; i < 8; ++i) m = max(m, v[i]);
    s[t] = m;
    if (t == 0) cnt = 0;
    __syncthreads();

    #pragma unroll
    for (int offd = 1; offd < 256; offd <<= 1) {
        int mine  = s[t];
        int other = (t >= offd) ? s[t - offd] : 0;
        __syncthreads();
        s[t] = max(mine, other);
        __syncthreads();
    }

    int run = (t > 0) ? s[t - 1] : 0;
    #pragma unroll
    for (int i = 0; i < 8; ++i) {
        run = max(run, v[i]);
        F[t * 8 + i] = run;
    }
    __syncthreads();

    // Phase 2: compact missing rows (F[l] != l; note F[0]==idx[0] so row 0
    // never lands in the list — kernel A already wrote it).
    #pragma unroll
    for (int i = 0; i < 8; ++i) {
        const int l = t * 8 + i;
        if (F[l] != l) {
            const int p = atomicAdd(&cnt, 1);
            list[p] = l;
        }
    }
    __syncthreads();

    // Phase 3: gather-copy. 8 groups of 32 lanes; one row per group-iteration.
    const int n    = cnt;
    const int grp  = t >> 5;
    const int lane = t & 31;
    const float4* xb = (const float4*)(x   + (size_t)b * Ln * Dn);
    float4*       ob = (float4*)      (out + (size_t)b * Ln * Dn);
    for (int i = grp; i < n; i += 8) {
        const int l  = list[i];
        const int Fv = F[l];
        ob[(size_t)l * 32 + lane] = xb[(size_t)Fv * 32 + lane];
    }
}

extern "C" void kernel_launch(void* const* d_in, const int* in_sizes, int n_in,
                              void* d_out, int out_size, void* d_ws, size_t ws_size,
                              hipStream_t stream) {
    const float* x = (const float*)d_in[0];
    float* out     = (float*)d_out;
    int* idx       = (int*)d_ws;            // Bn*Ln*4 = 2 MB of ws

    kernelA <<<A_BLOCKS, 256, 0, stream>>>(x, out, idx);
    kernelBC<<<Bn,       256, 0, stream>>>(x, out, idx);
}